// Round 1
// 566.665 us; speedup vs baseline: 1.4205x; 1.4205x over previous
//
#include <hip/hip_runtime.h>
#include <cstdint>
#include <cstddef>

namespace {

constexpr int kB  = 16;
constexpr int kC  = 512;
constexpr int kCQ = 64;    // C/8
constexpr int kCV = 256;   // C/2
constexpr int kN  = 4096;  // 64*64 spatial
constexpr int kM  = 1024;  // 32*32 pooled spatial

typedef _Float16 f16;
typedef _Float16 f16x8 __attribute__((ext_vector_type(8)));
typedef float    f32x4 __attribute__((ext_vector_type(4)));

// ---------------------------------------------------------------------------
// Kernel 0: weight conversion.
//   wcat = (f16) [wq; wk; wv]   [384][512]
//   woh  = (f16)(gamma * wo)    [512][256]
// Grid: 320 blocks x 256 (49152 float4 groups for wcat + 32768 for woh).
// ---------------------------------------------------------------------------
__global__ __launch_bounds__(256)
void convert_weights_kernel(const float* __restrict__ wq,
                            const float* __restrict__ wk,
                            const float* __restrict__ wv,
                            const float* __restrict__ wo,
                            const float* __restrict__ gamma,
                            f16* __restrict__ wcat,
                            f16* __restrict__ woh)
{
    const int idx = blockIdx.x * 256 + threadIdx.x;   // float4-group id
    if (idx < 49152) {
        const int e = idx * 4;
        const int r = e >> 9, c = e & 511;
        const float* src = (r < 64)  ? (wq + ((size_t)r << 9))
                         : (r < 128) ? (wk + ((size_t)(r - 64) << 9))
                                     : (wv + ((size_t)(r - 128) << 9));
        float4 v = *(const float4*)(src + c);
        union { f16 h4[4]; uint2 u; } pk;
        pk.h4[0] = (f16)v.x;
        pk.h4[1] = (f16)v.y;
        pk.h4[2] = (f16)v.z;
        pk.h4[3] = (f16)v.w;
        *(uint2*)(wcat + e) = pk.u;
    } else {
        const int e = (idx - 49152) * 4;
        const float g = gamma[0];
        float4 v = *(const float4*)(wo + e);
        union { f16 h4[4]; uint2 u; } pk;
        pk.h4[0] = (f16)(g * v.x);
        pk.h4[1] = (f16)(g * v.y);
        pk.h4[2] = (f16)(g * v.z);
        pk.h4[3] = (f16)(g * v.w);
        *(uint2*)(woh + e) = pk.u;
    }
}

// ---------------------------------------------------------------------------
// Kernel 1: MFMA projection GEMM + fused 2x2 maxpool.
//   Out[128 ch][128 n] tile = wcat[mt*128..][512] @ x_b[512][nt*128..] via
//   mfma_f32_16x16x32_f16, fp32 accum.  Grid: (nt=32, mt=0..2, b=16), 256 thr.
//   mt0 rows 0..63 -> fT (unpooled), rows 64..127 -> gT (pooled);
//   mt1/mt2       -> h channels (mt-1)*128.. (pooled).
// Wave layout: 4 waves = 2(row)x2(col); wave cols are the SPLIT pair
//   {wc*32 .. +31} U {64+wc*32 .. +31} so maxpool's y-partner columns
//   (c, c+64) live in the same lane (tile pairs tj / tj+2); x-partner
//   (c, c+1) is lane lq^1 -> one shfl_xor.
// ---------------------------------------------------------------------------
__global__ __launch_bounds__(256)
void proj_pool_mfma(const float* __restrict__ x,
                    const f16* __restrict__ wcat,
                    f16* __restrict__ fT,   // [B][4096][64]
                    f16* __restrict__ gT,   // [B][1024][64]
                    f16* __restrict__ h)    // [B][256][1024]
{
    const int nt  = blockIdx.x;   // 0..31: cols nt*128.. (spatial rows 2nt,2nt+1)
    const int mt  = blockIdx.y;   // 0..2 : output-channel tile of 128
    const int b   = blockIdx.z;
    const int tid = threadIdx.x;
    const int w    = tid >> 6;
    const int lane = tid & 63;
    const int quad = lane >> 4;
    const int lq   = lane & 15;
    const int wr   = w >> 1;      // row half (64 ch)
    const int wc   = w & 1;       // col half (32+32 split cols)

    // pad 40: row stride 80 B -> ~2-way bank aliasing on b128 read/write (free)
    __shared__ alignas(16) f16 As[128 * 40];  // [ch][k]  (k contiguous)
    __shared__ alignas(16) f16 Bs[128 * 40];  // [n][k]   (transposed x, f16)

    const f16*   Ab = wcat + (size_t)mt * 128 * kC;
    const float* Xb = x + (size_t)b * kC * kN + nt * 128;

    f32x4 acc[4][4];
#pragma unroll
    for (int i = 0; i < 4; ++i)
#pragma unroll
        for (int j = 0; j < 4; ++j) acc[i][j] = {0.f, 0.f, 0.f, 0.f};

    const int sr = tid >> 1;        // A row / B col n : 0..127
    const int sk = (tid & 1) * 16;  // k-half within 32-k tile

    for (int ks = 0; ks < 16; ++ks) {
        const int k0 = ks * 32;
        __syncthreads();   // previous iteration's frag reads done
        {   // ---- stage A: [128 ch][32 k] f16 (L2-resident weights) ----
            const f16* ap = Ab + (size_t)sr * kC + k0 + sk;
            uint4 a0 = *(const uint4*)ap;
            uint4 a1 = *(const uint4*)(ap + 8);
            *(uint4*)&As[sr * 40 + sk]     = a0;
            *(uint4*)&As[sr * 40 + sk + 8] = a1;
        }
        {   // ---- stage B: transpose x[32 k][128 n] -> Bs[n][k], f16 convert ----
            const float* xp = Xb + (size_t)(k0 + sk) * kN + sr;
            f16 tmp[16];
#pragma unroll
            for (int j = 0; j < 16; ++j)
                tmp[j] = (f16)xp[j * kN];   // scalar dword loads, coalesced over lanes
            *(uint4*)&Bs[sr * 40 + sk]     = *(uint4*)&tmp[0];
            *(uint4*)&Bs[sr * 40 + sk + 8] = *(uint4*)&tmp[8];
        }
        __syncthreads();

        f16x8 af[4], bs[4];
#pragma unroll
        for (int ti = 0; ti < 4; ++ti)
            af[ti] = *(const f16x8*)&As[(wr * 64 + ti * 16 + lq) * 40 + quad * 8];
#pragma unroll
        for (int tj = 0; tj < 4; ++tj) {
            const int col = (tj < 2) ? (wc * 32 + tj * 16 + lq)
                                     : (64 + wc * 32 + (tj - 2) * 16 + lq);
            bs[tj] = *(const f16x8*)&Bs[col * 40 + quad * 8];
        }
#pragma unroll
        for (int ti = 0; ti < 4; ++ti)
#pragma unroll
            for (int tj = 0; tj < 4; ++tj)
                acc[ti][tj] = __builtin_amdgcn_mfma_f32_16x16x32_f16(
                    af[ti], bs[tj], acc[ti][tj], 0, 0, 0);
    }

    // ---- epilogues.  D layout: row(ch) = quad*4+r, col(n) = lq per tile ----
    if (mt == 0 && wr == 0) {
        // f: unpooled, fT[n][ch], 8B stores (4 consecutive ch)
        f16* fb = fT + (size_t)b * kN * kCQ;
#pragma unroll
        for (int tj = 0; tj < 4; ++tj) {
            const int col = (tj < 2) ? (wc * 32 + tj * 16 + lq)
                                     : (64 + wc * 32 + (tj - 2) * 16 + lq);
            const int n = nt * 128 + col;
#pragma unroll
            for (int ti = 0; ti < 4; ++ti) {
                union { f16 h4[4]; uint2 u; } pk;
#pragma unroll
                for (int r = 0; r < 4; ++r) pk.h4[r] = (f16)acc[ti][tj][r];
                *(uint2*)(fb + (size_t)n * kCQ + ti * 16 + quad * 4) = pk.u;
            }
        }
    } else {
        // pooled paths: y-pair = (tj, tj+2), x-pair = lane lq^1
#pragma unroll
        for (int ti = 0; ti < 4; ++ti) {
#pragma unroll
            for (int tjp = 0; tjp < 2; ++tjp) {
                float p[4];
#pragma unroll
                for (int r = 0; r < 4; ++r) {
                    float v = fmaxf(acc[ti][tjp][r], acc[ti][tjp + 2][r]);
                    v = fmaxf(v, __shfl_xor(v, 1, 64));
                    p[r] = v;
                }
                const int m = nt * 32 + wc * 16 + tjp * 8 + (lq >> 1);
                if ((lq & 1) == 0) {
                    if (mt == 0) {
                        // g: gT[m][ch], ch = ti*16 + quad*4 + r
                        union { f16 h4[4]; uint2 u; } pk;
#pragma unroll
                        for (int r = 0; r < 4; ++r) pk.h4[r] = (f16)p[r];
                        *(uint2*)(gT + ((size_t)b * kM + m) * kCQ + ti * 16 + quad * 4) = pk.u;
                    } else {
                        // h: [ch][m] layout, scalar f16 stores
#pragma unroll
                        for (int r = 0; r < 4; ++r) {
                            const int ch = (mt - 1) * 128 + wr * 64 + ti * 16 + quad * 4 + r;
                            h[((size_t)b * kCV + ch) * kM + m] = (f16)p[r];
                        }
                    }
                }
            }
        }
    }
}

// ---------------------------------------------------------------------------
// Kernel 2: MFMA flash attention + fused wo GEMM + residual.  (unchanged)
// ---------------------------------------------------------------------------
__global__ __launch_bounds__(256, 3)
void attn_out_kernel(const f16* __restrict__ fT,
                     const f16* __restrict__ gT,
                     const f16* __restrict__ hmat,
                     const f16* __restrict__ woh,   // gamma*wo, f16 [512][256]
                     const float* __restrict__ x,
                     float* __restrict__ out)
{
    const int qt   = blockIdx.x;
    const int b    = blockIdx.y;
    const int tid  = threadIdx.x;
    const int w    = tid >> 6;
    const int lane = tid & 63;
    const int quad = lane >> 4;
    const int lq   = lane & 15;

    __shared__ union alignas(16) SMem {
        struct {
            f16   fsT[64 * 72];    // [q][ch], pad 72: bank stride 4 -> 2-way (free)
            f16   gsT[32 * 64];    // [m][ch], XOR-swizzled 16B units
            f16   hs[256 * 40];    // [c][m-chunk], pad 40: bank stride 20 -> 2-way
            f16   ps[64 * 40];     // [q][m-chunk], pad 40
            float al[64];          // per-q alpha (this chunk)
            float rl[64];          // per-q final l
        } p1;                      // 39424 B
        struct {
            f16 osT[4 * 16 * 264]; // [q-local][c], pad 264 per row
            f16 wos[256 * 40];     // [oc'][k-slab], pad 40
        } p2;                      // 54272 B
    } sm;

    // ---- stage fsT [64 q][64 ch] (8 KB) ----
    {
        const f16* fb = fT + ((size_t)b * kN + qt * 64) * kCQ;
#pragma unroll
        for (int p = 0; p < 2; ++p) {
            const int unit = tid + p * 256;
            const int q = unit >> 3, u = unit & 7;
            *(uint4*)&sm.p1.fsT[q * 72 + u * 8] = *(const uint4*)(fb + q * 64 + u * 8);
        }
    }
    __syncthreads();

    // loop-invariant A-frags of f (q = w*16+lq, ch = kb*32 + quad*8 + j)
    const f16x8 af0 = *(const f16x8*)&sm.p1.fsT[(w * 16 + lq) * 72 + quad * 8];
    const f16x8 af1 = *(const f16x8*)&sm.p1.fsT[(w * 16 + lq) * 72 + 32 + quad * 8];

    float m_run[4] = {-3.0e38f, -3.0e38f, -3.0e38f, -3.0e38f};
    float l_run[4] = {0.f, 0.f, 0.f, 0.f};
    f32x4 o_acc[16];
#pragma unroll
    for (int ci = 0; ci < 16; ++ci) o_acc[ci] = {0.f, 0.f, 0.f, 0.f};

    const f16* gTb = gT + (size_t)b * kM * kCQ;
    const f16* hb  = hmat + (size_t)b * kCV * kM;

    for (int mi = 0; mi < 32; ++mi) {
        const int m0 = mi * 32;
        __syncthreads();   // prior chunk's PV reads of hs done

        // ---- stage gsT [32 m][64 ch], XOR-swizzle 16B units ----
        {
            const int m = tid >> 3, su = tid & 7;
            const int gu = su ^ (m & 7);
            *(uint4*)&sm.p1.gsT[m * 64 + su * 8] =
                *(const uint4*)(gTb + (size_t)(m0 + m) * kCQ + gu * 8);
        }
        // ---- stage hs [256 c][32 m] ----
#pragma unroll
        for (int p = 0; p < 4; ++p) {
            const int c = (tid >> 2) + p * 64, u = tid & 3;
            *(uint4*)&sm.p1.hs[c * 40 + u * 8] =
                *(const uint4*)(hb + (size_t)c * kM + m0 + u * 8);
        }
        __syncthreads();

        // ---- S = f^T g : wave w -> 16q x 32m, K=64 ----
        const int mr0 = lq, mr1 = 16 + lq;
        const f16x8 bg00 = *(const f16x8*)&sm.p1.gsT[mr0 * 64 + ((quad)     ^ (mr0 & 7)) * 8];
        const f16x8 bg01 = *(const f16x8*)&sm.p1.gsT[mr0 * 64 + ((4 + quad) ^ (mr0 & 7)) * 8];
        const f16x8 bg10 = *(const f16x8*)&sm.p1.gsT[mr1 * 64 + ((quad)     ^ (mr1 & 7)) * 8];
        const f16x8 bg11 = *(const f16x8*)&sm.p1.gsT[mr1 * 64 + ((4 + quad) ^ (mr1 & 7)) * 8];
        f32x4 s0 = {0.f, 0.f, 0.f, 0.f}, s1 = {0.f, 0.f, 0.f, 0.f};
        s0 = __builtin_amdgcn_mfma_f32_16x16x32_f16(af0, bg00, s0, 0, 0, 0);
        s0 = __builtin_amdgcn_mfma_f32_16x16x32_f16(af1, bg01, s0, 0, 0, 0);
        s1 = __builtin_amdgcn_mfma_f32_16x16x32_f16(af0, bg10, s1, 0, 0, 0);
        s1 = __builtin_amdgcn_mfma_f32_16x16x32_f16(af1, bg11, s1, 0, 0, 0);

        // ---- online softmax: row q = w*16 + quad*4 + r lives in this quad ----
#pragma unroll
        for (int r = 0; r < 4; ++r) {
            float cm = fmaxf(s0[r], s1[r]);
            cm = fmaxf(cm, __shfl_xor(cm, 1, 64));
            cm = fmaxf(cm, __shfl_xor(cm, 2, 64));
            cm = fmaxf(cm, __shfl_xor(cm, 4, 64));
            cm = fmaxf(cm, __shfl_xor(cm, 8, 64));
            const float nm = fmaxf(m_run[r], cm);
            const float al = __expf(m_run[r] - nm);   // mi==0: exp(-huge)=0
            const float p0 = __expf(s0[r] - nm);
            const float p1 = __expf(s1[r] - nm);
            float psum = p0 + p1;
            psum += __shfl_xor(psum, 1, 64);
            psum += __shfl_xor(psum, 2, 64);
            psum += __shfl_xor(psum, 4, 64);
            psum += __shfl_xor(psum, 8, 64);
            m_run[r] = nm;
            l_run[r] = l_run[r] * al + psum;
            if (lq == 0) sm.p1.al[w * 16 + quad * 4 + r] = al;
            sm.p1.ps[(w * 16 + quad * 4 + r) * 40 + lq]      = (f16)p0;
            sm.p1.ps[(w * 16 + quad * 4 + r) * 40 + 16 + lq] = (f16)p1;
        }

        // ---- PV: o[c][q] = alpha*o + h @ P^T  (wave-local ps/al, in-order LDS) ----
        const float alv = sm.p1.al[w * 16 + lq];
        const f16x8 bp  = *(const f16x8*)&sm.p1.ps[(w * 16 + lq) * 40 + quad * 8];
#pragma unroll
        for (int ci = 0; ci < 16; ++ci) {
            const f16x8 ha = *(const f16x8*)&sm.p1.hs[(ci * 16 + lq) * 40 + quad * 8];
            o_acc[ci] *= alv;
            o_acc[ci] = __builtin_amdgcn_mfma_f32_16x16x32_f16(ha, bp, o_acc[ci], 0, 0, 0);
        }
    }

    // ---- normalize; o -> LDS as f16 osT[q-local][c] ----
    if (lq == 0) {
#pragma unroll
        for (int r = 0; r < 4; ++r) sm.p1.rl[w * 16 + quad * 4 + r] = l_run[r];
    }
    const float inv = 1.0f / sm.p1.rl[w * 16 + lq];   // read BEFORE clobber barrier
    __syncthreads();
#pragma unroll
    for (int ci = 0; ci < 16; ++ci)
#pragma unroll
        for (int r = 0; r < 4; ++r)
            sm.p2.osT[(w * 16 + lq) * 264 + ci * 16 + quad * 4 + r] =
                (f16)(o_acc[ci][r] * inv);
    __syncthreads();

    // ---- GEMM2: out = woh @ o + x  (512 oc in 2 halves; K=256 in 8 slabs) ----
    for (int half = 0; half < 2; ++half) {
        f32x4 acc2[16];
#pragma unroll
        for (int os = 0; os < 16; ++os) acc2[os] = {0.f, 0.f, 0.f, 0.f};

        for (int ck = 0; ck < 8; ++ck) {
            __syncthreads();   // prev slab reads done
#pragma unroll
            for (int p = 0; p < 4; ++p) {
                const int oc = (tid >> 2) + p * 64, u = tid & 3;
                *(uint4*)&sm.p2.wos[oc * 40 + u * 8] =
                    *(const uint4*)(woh + (size_t)(half * 256 + oc) * 256 + ck * 32 + u * 8);
            }
            __syncthreads();
            const f16x8 bo = *(const f16x8*)&sm.p2.osT[(w * 16 + lq) * 264 + ck * 32 + quad * 8];
#pragma unroll
            for (int os = 0; os < 16; ++os) {
                const f16x8 wa = *(const f16x8*)&sm.p2.wos[(os * 16 + lq) * 40 + quad * 8];
                acc2[os] = __builtin_amdgcn_mfma_f32_16x16x32_f16(wa, bo, acc2[os], 0, 0, 0);
            }
        }

        const int n0 = qt * 64 + w * 16 + lq;
#pragma unroll
        for (int os = 0; os < 16; ++os) {
#pragma unroll
            for (int r = 0; r < 4; ++r) {
                const int oc = half * 256 + os * 16 + quad * 4 + r;
                const size_t idx = ((size_t)b * kC + oc) * (size_t)kN + n0;
                out[idx] = acc2[os][r] + x[idx];
            }
        }
    }
}

}  // namespace

extern "C" void kernel_launch(void* const* d_in, const int* in_sizes, int n_in,
                              void* d_out, int out_size, void* d_ws, size_t ws_size,
                              hipStream_t stream) {
    const float* x     = (const float*)d_in[0];
    const float* wq    = (const float*)d_in[1];
    const float* wk    = (const float*)d_in[2];
    const float* wv    = (const float*)d_in[3];
    const float* wo    = (const float*)d_in[4];
    const float* gamma = (const float*)d_in[5];
    float* out = (float*)d_out;

    // f16 workspace: fT [16][4096][64], gT [16][1024][64], h [16][256][1024],
    // woh [512][256], wcat [384][512]  -> 19.5 MB total
    f16* fT   = (f16*)d_ws;
    f16* gT   = fT  + (size_t)kB * kN * kCQ;    // +4,194,304 el
    f16* hw   = gT  + (size_t)kB * kM * kCQ;    // +1,048,576 el
    f16* woh  = hw  + (size_t)kB * kCV * kM;    // +4,194,304 el
    f16* wcat = woh + (size_t)kC * kCV;         // +131,072 el

    hipLaunchKernelGGL(convert_weights_kernel, dim3(320), dim3(256), 0, stream,
                       wq, wk, wv, wo, gamma, wcat, woh);
    hipLaunchKernelGGL(proj_pool_mfma, dim3(32, 3, kB), dim3(256), 0, stream,
                       x, wcat, fT, gT, hw);
    hipLaunchKernelGGL(attn_out_kernel, dim3(64, kB), dim3(256), 0, stream,
                       fT, gT, hw, woh, x, out);
}

// Round 2
// 523.898 us; speedup vs baseline: 1.5365x; 1.0816x over previous
//
#include <hip/hip_runtime.h>
#include <cstdint>
#include <cstddef>

namespace {

constexpr int kB  = 16;
constexpr int kC  = 512;
constexpr int kCQ = 64;    // C/8
constexpr int kCV = 256;   // C/2
constexpr int kN  = 4096;  // 64*64 spatial
constexpr int kM  = 1024;  // 32*32 pooled spatial

typedef _Float16 f16;
typedef _Float16 f16x8 __attribute__((ext_vector_type(8)));
typedef float    f32x4 __attribute__((ext_vector_type(4)));

// ---------------------------------------------------------------------------
// Kernel 0: weight conversion.
//   wcat = (f16) [wq; wk; wv]   [384][512]
//   woh  = (f16)(gamma * wo)    [512][256]
// ---------------------------------------------------------------------------
__global__ __launch_bounds__(256)
void convert_weights_kernel(const float* __restrict__ wq,
                            const float* __restrict__ wk,
                            const float* __restrict__ wv,
                            const float* __restrict__ wo,
                            const float* __restrict__ gamma,
                            f16* __restrict__ wcat,
                            f16* __restrict__ woh)
{
    const int idx = blockIdx.x * 256 + threadIdx.x;   // float4-group id
    if (idx < 49152) {
        const int e = idx * 4;
        const int r = e >> 9, c = e & 511;
        const float* src = (r < 64)  ? (wq + ((size_t)r << 9))
                         : (r < 128) ? (wk + ((size_t)(r - 64) << 9))
                                     : (wv + ((size_t)(r - 128) << 9));
        float4 v = *(const float4*)(src + c);
        union { f16 h4[4]; uint2 u; } pk;
        pk.h4[0] = (f16)v.x;
        pk.h4[1] = (f16)v.y;
        pk.h4[2] = (f16)v.z;
        pk.h4[3] = (f16)v.w;
        *(uint2*)(wcat + e) = pk.u;
    } else {
        const int e = (idx - 49152) * 4;
        const float g = gamma[0];
        float4 v = *(const float4*)(wo + e);
        union { f16 h4[4]; uint2 u; } pk;
        pk.h4[0] = (f16)(g * v.x);
        pk.h4[1] = (f16)(g * v.y);
        pk.h4[2] = (f16)(g * v.z);
        pk.h4[3] = (f16)(g * v.w);
        *(uint2*)(woh + e) = pk.u;
    }
}

// ---------------------------------------------------------------------------
// Kernel 1: MFMA projection GEMM + fused 2x2 maxpool, reg-prefetch staging.
//   Grid: (nt=32, mt=0..2, b=16), 256 thr.
// ---------------------------------------------------------------------------
__global__ __launch_bounds__(256)
void proj_pool_mfma(const float* __restrict__ x,
                    const f16* __restrict__ wcat,
                    f16* __restrict__ fT,   // [B][4096][64]
                    f16* __restrict__ gT,   // [B][1024][64]
                    f16* __restrict__ h)    // [B][256][1024]
{
    const int nt  = blockIdx.x;
    const int mt  = blockIdx.y;
    const int b   = blockIdx.z;
    const int tid = threadIdx.x;
    const int w    = tid >> 6;
    const int lane = tid & 63;
    const int quad = lane >> 4;
    const int lq   = lane & 15;
    const int wr   = w >> 1;
    const int wc   = w & 1;

    __shared__ alignas(16) f16 As[128 * 40];  // [ch][k]
    __shared__ alignas(16) f16 Bs[128 * 40];  // [n][k]

    const f16*   Ab = wcat + (size_t)mt * 128 * kC;
    const float* Xb = x + (size_t)b * kC * kN + nt * 128;

    f32x4 acc[4][4];
#pragma unroll
    for (int i = 0; i < 4; ++i)
#pragma unroll
        for (int j = 0; j < 4; ++j) acc[i][j] = {0.f, 0.f, 0.f, 0.f};

    const int sr = tid >> 1;        // A row / B col n : 0..127
    const int sk = (tid & 1) * 16;  // k-half within 32-k tile

    // ---- prefetch registers ----
    uint4 pa0, pa1;
    float tb[16];
    {   // LOAD ks=0
        const f16* ap = Ab + (size_t)sr * kC + sk;
        pa0 = *(const uint4*)ap;
        pa1 = *(const uint4*)(ap + 8);
        const float* xp = Xb + (size_t)sk * kN + sr;
#pragma unroll
        for (int j = 0; j < 16; ++j) tb[j] = xp[j * kN];
    }

    for (int ks = 0; ks < 16; ++ks) {
        __syncthreads();   // previous iteration's frag reads done
        // ---- write staged regs -> LDS ----
        *(uint4*)&As[sr * 40 + sk]     = pa0;
        *(uint4*)&As[sr * 40 + sk + 8] = pa1;
        {
            f16 tmp[16];
#pragma unroll
            for (int j = 0; j < 16; ++j) tmp[j] = (f16)tb[j];
            *(uint4*)&Bs[sr * 40 + sk]     = *(uint4*)&tmp[0];
            *(uint4*)&Bs[sr * 40 + sk + 8] = *(uint4*)&tmp[8];
        }
        __syncthreads();
        // ---- issue next tile's loads (latency hides under MFMA) ----
        if (ks < 15) {
            const int k0 = (ks + 1) * 32;
            const f16* ap = Ab + (size_t)sr * kC + k0 + sk;
            pa0 = *(const uint4*)ap;
            pa1 = *(const uint4*)(ap + 8);
            const float* xp = Xb + (size_t)(k0 + sk) * kN + sr;
#pragma unroll
            for (int j = 0; j < 16; ++j) tb[j] = xp[j * kN];
        }

        f16x8 af[4], bs[4];
#pragma unroll
        for (int ti = 0; ti < 4; ++ti)
            af[ti] = *(const f16x8*)&As[(wr * 64 + ti * 16 + lq) * 40 + quad * 8];
#pragma unroll
        for (int tj = 0; tj < 4; ++tj) {
            const int col = (tj < 2) ? (wc * 32 + tj * 16 + lq)
                                     : (64 + wc * 32 + (tj - 2) * 16 + lq);
            bs[tj] = *(const f16x8*)&Bs[col * 40 + quad * 8];
        }
        __builtin_amdgcn_s_setprio(1);
#pragma unroll
        for (int ti = 0; ti < 4; ++ti)
#pragma unroll
            for (int tj = 0; tj < 4; ++tj)
                acc[ti][tj] = __builtin_amdgcn_mfma_f32_16x16x32_f16(
                    af[ti], bs[tj], acc[ti][tj], 0, 0, 0);
        __builtin_amdgcn_s_setprio(0);
    }

    // ---- epilogues (unchanged) ----
    if (mt == 0 && wr == 0) {
        f16* fb = fT + (size_t)b * kN * kCQ;
#pragma unroll
        for (int tj = 0; tj < 4; ++tj) {
            const int col = (tj < 2) ? (wc * 32 + tj * 16 + lq)
                                     : (64 + wc * 32 + (tj - 2) * 16 + lq);
            const int n = nt * 128 + col;
#pragma unroll
            for (int ti = 0; ti < 4; ++ti) {
                union { f16 h4[4]; uint2 u; } pk;
#pragma unroll
                for (int r = 0; r < 4; ++r) pk.h4[r] = (f16)acc[ti][tj][r];
                *(uint2*)(fb + (size_t)n * kCQ + ti * 16 + quad * 4) = pk.u;
            }
        }
    } else {
#pragma unroll
        for (int ti = 0; ti < 4; ++ti) {
#pragma unroll
            for (int tjp = 0; tjp < 2; ++tjp) {
                float p[4];
#pragma unroll
                for (int r = 0; r < 4; ++r) {
                    float v = fmaxf(acc[ti][tjp][r], acc[ti][tjp + 2][r]);
                    v = fmaxf(v, __shfl_xor(v, 1, 64));
                    p[r] = v;
                }
                const int m = nt * 32 + wc * 16 + tjp * 8 + (lq >> 1);
                if ((lq & 1) == 0) {
                    if (mt == 0) {
                        union { f16 h4[4]; uint2 u; } pk;
#pragma unroll
                        for (int r = 0; r < 4; ++r) pk.h4[r] = (f16)p[r];
                        *(uint2*)(gT + ((size_t)b * kM + m) * kCQ + ti * 16 + quad * 4) = pk.u;
                    } else {
#pragma unroll
                        for (int r = 0; r < 4; ++r) {
                            const int ch = (mt - 1) * 128 + wr * 64 + ti * 16 + quad * 4 + r;
                            h[((size_t)b * kCV + ch) * kM + m] = (f16)p[r];
                        }
                    }
                }
            }
        }
    }
}

// ---------------------------------------------------------------------------
// Kernel 2: MFMA flash attention + fused wo GEMM + residual.
//   NEW: swapped-S (S^T = g@f) so softmax is per-lane (q = lq): 2 shuffles
//   instead of 32, alpha/l in registers, vectorized P stores.
//   NEW: register-prefetch of next chunk's gT/h tiles and next woh slab.
// ---------------------------------------------------------------------------
__global__ __launch_bounds__(256, 3)
void attn_out_kernel(const f16* __restrict__ fT,
                     const f16* __restrict__ gT,
                     const f16* __restrict__ hmat,
                     const f16* __restrict__ woh,   // gamma*wo, f16 [512][256]
                     const float* __restrict__ x,
                     float* __restrict__ out)
{
    const int qt   = blockIdx.x;
    const int b    = blockIdx.y;
    const int tid  = threadIdx.x;
    const int w    = tid >> 6;
    const int lane = tid & 63;
    const int quad = lane >> 4;
    const int lq   = lane & 15;

    __shared__ union alignas(16) SMem {
        struct {
            f16   fsT[64 * 72];    // [q][ch]
            f16   gsT[32 * 64];    // [m][ch], XOR-swizzled 16B units
            f16   hs[256 * 40];    // [c][m-chunk]
            f16   ps[64 * 40];     // [q][m-chunk]
        } p1;                      // 38912 B
        struct {
            f16 osT[4 * 16 * 264]; // [q-local][c]
            f16 wos[256 * 40];     // [oc'][k-slab]
        } p2;                      // 54272 B
    } sm;

    // ---- stage fsT [64 q][64 ch] ----
    {
        const f16* fb = fT + ((size_t)b * kN + qt * 64) * kCQ;
#pragma unroll
        for (int p = 0; p < 2; ++p) {
            const int unit = tid + p * 256;
            const int q = unit >> 3, u = unit & 7;
            *(uint4*)&sm.p1.fsT[q * 72 + u * 8] = *(const uint4*)(fb + q * 64 + u * 8);
        }
    }
    __syncthreads();

    // loop-invariant f frags (q = w*16+lq, ch = kb*32 + quad*8 + j)
    const f16x8 af0 = *(const f16x8*)&sm.p1.fsT[(w * 16 + lq) * 72 + quad * 8];
    const f16x8 af1 = *(const f16x8*)&sm.p1.fsT[(w * 16 + lq) * 72 + 32 + quad * 8];

    float m_run = -3.0e38f, l_run = 0.f;   // per-lane: q = w*16 + lq
    f32x4 o_acc[16];
#pragma unroll
    for (int ci = 0; ci < 16; ++ci) o_acc[ci] = {0.f, 0.f, 0.f, 0.f};

    const f16* gTb = gT + (size_t)b * kM * kCQ;
    const f16* hb  = hmat + (size_t)b * kCV * kM;

    // ---- prefetch registers for chunk staging ----
    const int gm = tid >> 3, gsu = tid & 7, ggu = gsu ^ (gm & 7);
    const int hc = tid >> 2, hu = tid & 3;
    uint4 pg, ph[4];
    {   // LOAD chunk 0
        pg = *(const uint4*)(gTb + (size_t)gm * kCQ + ggu * 8);
#pragma unroll
        for (int p = 0; p < 4; ++p)
            ph[p] = *(const uint4*)(hb + (size_t)(hc + p * 64) * kM + hu * 8);
    }

    for (int mi = 0; mi < 32; ++mi) {
        __syncthreads();   // prior chunk's LDS reads done
        // ---- write staged regs -> LDS ----
        *(uint4*)&sm.p1.gsT[gm * 64 + gsu * 8] = pg;
#pragma unroll
        for (int p = 0; p < 4; ++p)
            *(uint4*)&sm.p1.hs[(hc + p * 64) * 40 + hu * 8] = ph[p];
        __syncthreads();
        // ---- issue next chunk's loads ----
        if (mi < 31) {
            const int m1 = (mi + 1) * 32;
            pg = *(const uint4*)(gTb + (size_t)(m1 + gm) * kCQ + ggu * 8);
#pragma unroll
            for (int p = 0; p < 4; ++p)
                ph[p] = *(const uint4*)(hb + (size_t)(hc + p * 64) * kM + m1 + hu * 8);
        }

        // ---- S^T = g @ f : D[m=quad*4+r (+16)][q=lq] ----
        const int mr0 = lq, mr1 = 16 + lq;
        const f16x8 bg00 = *(const f16x8*)&sm.p1.gsT[mr0 * 64 + ((quad)     ^ (mr0 & 7)) * 8];
        const f16x8 bg01 = *(const f16x8*)&sm.p1.gsT[mr0 * 64 + ((4 + quad) ^ (mr0 & 7)) * 8];
        const f16x8 bg10 = *(const f16x8*)&sm.p1.gsT[mr1 * 64 + ((quad)     ^ (mr1 & 7)) * 8];
        const f16x8 bg11 = *(const f16x8*)&sm.p1.gsT[mr1 * 64 + ((4 + quad) ^ (mr1 & 7)) * 8];
        f32x4 s0 = {0.f, 0.f, 0.f, 0.f}, s1 = {0.f, 0.f, 0.f, 0.f};
        s0 = __builtin_amdgcn_mfma_f32_16x16x32_f16(bg00, af0, s0, 0, 0, 0);
        s0 = __builtin_amdgcn_mfma_f32_16x16x32_f16(bg01, af1, s0, 0, 0, 0);
        s1 = __builtin_amdgcn_mfma_f32_16x16x32_f16(bg10, af0, s1, 0, 0, 0);
        s1 = __builtin_amdgcn_mfma_f32_16x16x32_f16(bg11, af1, s1, 0, 0, 0);

        // ---- per-lane online softmax for q = w*16+lq (lane holds 8 m-vals) ----
        float cm = fmaxf(fmaxf(fmaxf(s0[0], s0[1]), fmaxf(s0[2], s0[3])),
                         fmaxf(fmaxf(s1[0], s1[1]), fmaxf(s1[2], s1[3])));
        cm = fmaxf(cm, __shfl_xor(cm, 16, 64));
        cm = fmaxf(cm, __shfl_xor(cm, 32, 64));
        const float nm = fmaxf(m_run, cm);
        const float al = __expf(m_run - nm);   // mi==0: exp(-huge)=0
        float e0[4], e1[4];
#pragma unroll
        for (int r = 0; r < 4; ++r) { e0[r] = __expf(s0[r] - nm); e1[r] = __expf(s1[r] - nm); }
        float psum = (e0[0] + e0[1]) + (e0[2] + e0[3]) + (e1[0] + e1[1]) + (e1[2] + e1[3]);
        psum += __shfl_xor(psum, 16, 64);
        psum += __shfl_xor(psum, 32, 64);
        m_run = nm;
        l_run = l_run * al + psum;

        // ---- P -> LDS ps[q][m]: two 8B stores (m = quad*4.. / 16+quad*4..) ----
        union { f16 h4[4]; uint2 u; } pk0, pk1;
#pragma unroll
        for (int r = 0; r < 4; ++r) { pk0.h4[r] = (f16)e0[r]; pk1.h4[r] = (f16)e1[r]; }
        *(uint2*)&sm.p1.ps[(w * 16 + lq) * 40 + quad * 4]      = pk0.u;
        *(uint2*)&sm.p1.ps[(w * 16 + lq) * 40 + 16 + quad * 4] = pk1.u;
        __builtin_amdgcn_sched_barrier(0);   // keep bp read after P stores

        // ---- PV: o[c][q] = al*o + h @ P  (wave-local rows of ps) ----
        const f16x8 bp = *(const f16x8*)&sm.p1.ps[(w * 16 + lq) * 40 + quad * 8];
        __builtin_amdgcn_s_setprio(1);
#pragma unroll
        for (int ci = 0; ci < 16; ++ci) {
            const f16x8 ha = *(const f16x8*)&sm.p1.hs[(ci * 16 + lq) * 40 + quad * 8];
            o_acc[ci] *= al;
            o_acc[ci] = __builtin_amdgcn_mfma_f32_16x16x32_f16(ha, bp, o_acc[ci], 0, 0, 0);
        }
        __builtin_amdgcn_s_setprio(0);
    }

    const float inv = 1.0f / l_run;          // per-lane, q = w*16+lq

    // ---- prefetch first woh slab (overlaps epilogue) ----
    const int woc = tid >> 2, wu = tid & 3;
    uint4 pw[4];
#pragma unroll
    for (int p = 0; p < 4; ++p)
        pw[p] = *(const uint4*)(woh + (size_t)(woc + p * 64) * 256 + wu * 8);

    __syncthreads();   // all waves done reading p1 before p2 clobber
#pragma unroll
    for (int ci = 0; ci < 16; ++ci)
#pragma unroll
        for (int r = 0; r < 4; ++r)
            sm.p2.osT[(w * 16 + lq) * 264 + ci * 16 + quad * 4 + r] =
                (f16)(o_acc[ci][r] * inv);

    // ---- GEMM2: out = woh @ o + x  (512 oc in 2 halves; K=256 in 8 slabs) ----
    for (int half = 0; half < 2; ++half) {
        f32x4 acc2[16];
#pragma unroll
        for (int os = 0; os < 16; ++os) acc2[os] = {0.f, 0.f, 0.f, 0.f};

        for (int ck = 0; ck < 8; ++ck) {
            __syncthreads();   // prev slab reads done
#pragma unroll
            for (int p = 0; p < 4; ++p)
                *(uint4*)&sm.p2.wos[(woc + p * 64) * 40 + wu * 8] = pw[p];
            __syncthreads();
            {   // issue next slab's loads
                const int s = half * 8 + ck + 1;
                if (s < 16) {
#pragma unroll
                    for (int p = 0; p < 4; ++p)
                        pw[p] = *(const uint4*)(woh +
                            (size_t)((s >> 3) * 256 + woc + p * 64) * 256 +
                            (s & 7) * 32 + wu * 8);
                }
            }
            const f16x8 bo = *(const f16x8*)&sm.p2.osT[(w * 16 + lq) * 264 + ck * 32 + quad * 8];
            __builtin_amdgcn_s_setprio(1);
#pragma unroll
            for (int os = 0; os < 16; ++os) {
                const f16x8 wa = *(const f16x8*)&sm.p2.wos[(os * 16 + lq) * 40 + quad * 8];
                acc2[os] = __builtin_amdgcn_mfma_f32_16x16x32_f16(wa, bo, acc2[os], 0, 0, 0);
            }
            __builtin_amdgcn_s_setprio(0);
        }

        const int n0 = qt * 64 + w * 16 + lq;
#pragma unroll
        for (int os = 0; os < 16; ++os) {
#pragma unroll
            for (int r = 0; r < 4; ++r) {
                const int oc = half * 256 + os * 16 + quad * 4 + r;
                const size_t idx = ((size_t)b * kC + oc) * (size_t)kN + n0;
                out[idx] = acc2[os][r] + x[idx];
            }
        }
    }
}

}  // namespace

extern "C" void kernel_launch(void* const* d_in, const int* in_sizes, int n_in,
                              void* d_out, int out_size, void* d_ws, size_t ws_size,
                              hipStream_t stream) {
    const float* x     = (const float*)d_in[0];
    const float* wq    = (const float*)d_in[1];
    const float* wk    = (const float*)d_in[2];
    const float* wv    = (const float*)d_in[3];
    const float* wo    = (const float*)d_in[4];
    const float* gamma = (const float*)d_in[5];
    float* out = (float*)d_out;

    f16* fT   = (f16*)d_ws;
    f16* gT   = fT  + (size_t)kB * kN * kCQ;
    f16* hw   = gT  + (size_t)kB * kM * kCQ;
    f16* woh  = hw  + (size_t)kB * kCV * kM;
    f16* wcat = woh + (size_t)kC * kCV;

    hipLaunchKernelGGL(convert_weights_kernel, dim3(320), dim3(256), 0, stream,
                       wq, wk, wv, wo, gamma, wcat, woh);
    hipLaunchKernelGGL(proj_pool_mfma, dim3(32, 3, kB), dim3(256), 0, stream,
                       x, wcat, fT, gT, hw);
    hipLaunchKernelGGL(attn_out_kernel, dim3(64, kB), dim3(256), 0, stream,
                       fT, gT, hw, woh, x, out);
}

// Round 3
// 472.350 us; speedup vs baseline: 1.7042x; 1.1091x over previous
//
#include <hip/hip_runtime.h>
#include <cstdint>
#include <cstddef>

namespace {

constexpr int kB  = 16;
constexpr int kC  = 512;
constexpr int kCQ = 64;    // C/8
constexpr int kCV = 256;   // C/2
constexpr int kN  = 4096;  // 64*64 spatial
constexpr int kM  = 1024;  // 32*32 pooled spatial

typedef _Float16 f16;
typedef _Float16 f16x8 __attribute__((ext_vector_type(8)));
typedef float    f32x4 __attribute__((ext_vector_type(4)));

// ---------------------------------------------------------------------------
// Kernel 0: weight conversion.
//   wcat = (f16) [wq; wk; wv]   [384][512]
//   woh  = (f16)(gamma * wo)    [512][256]
// ---------------------------------------------------------------------------
__global__ __launch_bounds__(256)
void convert_weights_kernel(const float* __restrict__ wq,
                            const float* __restrict__ wk,
                            const float* __restrict__ wv,
                            const float* __restrict__ wo,
                            const float* __restrict__ gamma,
                            f16* __restrict__ wcat,
                            f16* __restrict__ woh)
{
    const int idx = blockIdx.x * 256 + threadIdx.x;   // float4-group id
    if (idx < 49152) {
        const int e = idx * 4;
        const int r = e >> 9, c = e & 511;
        const float* src = (r < 64)  ? (wq + ((size_t)r << 9))
                         : (r < 128) ? (wk + ((size_t)(r - 64) << 9))
                                     : (wv + ((size_t)(r - 128) << 9));
        float4 v = *(const float4*)(src + c);
        union { f16 h4[4]; uint2 u; } pk;
        pk.h4[0] = (f16)v.x;
        pk.h4[1] = (f16)v.y;
        pk.h4[2] = (f16)v.z;
        pk.h4[3] = (f16)v.w;
        *(uint2*)(wcat + e) = pk.u;
    } else {
        const int e = (idx - 49152) * 4;
        const float g = gamma[0];
        float4 v = *(const float4*)(wo + e);
        union { f16 h4[4]; uint2 u; } pk;
        pk.h4[0] = (f16)(g * v.x);
        pk.h4[1] = (f16)(g * v.y);
        pk.h4[2] = (f16)(g * v.z);
        pk.h4[3] = (f16)(g * v.w);
        *(uint2*)(woh + e) = pk.u;
    }
}

// ---------------------------------------------------------------------------
// Kernel 1: MFMA projection GEMM + fused 2x2 maxpool.
//   CONSOLIDATED: one 512-thread block computes ALL 384 output channels for a
//   128-col tile (x staged once, not 3x).  Grid: (nt=32, b=16).
//   8 waves = 4 row-quarters (96 ch) x 2 col-halves (split pair for pooling).
// ---------------------------------------------------------------------------
__global__ __launch_bounds__(512, 2)
void proj_pool_mfma(const float* __restrict__ x,
                    const f16* __restrict__ wcat,
                    f16* __restrict__ fT,   // [B][4096][64]
                    f16* __restrict__ gT,   // [B][1024][64]
                    f16* __restrict__ h)    // [B][256][1024]
{
    const int nt  = blockIdx.x;
    const int b   = blockIdx.y;
    const int tid = threadIdx.x;
    const int w    = tid >> 6;
    const int lane = tid & 63;
    const int quad = lane >> 4;
    const int lq   = lane & 15;
    const int wr   = w >> 1;      // row quarter: 96 ch
    const int wc   = w & 1;       // col half (32+32 split cols)

    __shared__ alignas(16) f16 As[384 * 40];  // [ch][k]
    __shared__ alignas(16) f16 Bs[128 * 40];  // [n][k]   (transposed x, f16)

    const float* Xb = x + (size_t)b * kC * kN + nt * 128;

    f32x4 acc[6][4];
#pragma unroll
    for (int i = 0; i < 6; ++i)
#pragma unroll
        for (int j = 0; j < 4; ++j) acc[i][j] = {0.f, 0.f, 0.f, 0.f};

    // staging assignments
    const int bn = tid & 127;       // B row (n)
    const int kg = tid >> 7;        // B k-group: k = kg*8..+7

    // ---- prefetch registers (ks = 0) ----
    uint4 pa[3];
    float xv[8];
#pragma unroll
    for (int p = 0; p < 3; ++p) {
        const int unit = tid + p * 512;
        const int row = unit >> 2, su = unit & 3;
        pa[p] = *(const uint4*)(wcat + (size_t)row * kC + su * 8);
    }
#pragma unroll
    for (int j = 0; j < 8; ++j) xv[j] = Xb[(size_t)(kg * 8 + j) * kN + bn];

    for (int ks = 0; ks < 16; ++ks) {
        __syncthreads();   // previous iteration's frag reads done
        // ---- write staged regs -> LDS ----
#pragma unroll
        for (int p = 0; p < 3; ++p) {
            const int unit = tid + p * 512;
            const int row = unit >> 2, su = unit & 3;
            *(uint4*)&As[row * 40 + su * 8] = pa[p];
        }
        {
            union { f16 hh[8]; uint4 u; } pk;
#pragma unroll
            for (int j = 0; j < 8; ++j) pk.hh[j] = (f16)xv[j];
            *(uint4*)&Bs[bn * 40 + kg * 8] = pk.u;
        }
        __syncthreads();
        // ---- issue next tile's loads (hide under MFMA) ----
        if (ks < 15) {
            const int k0 = (ks + 1) * 32;
#pragma unroll
            for (int p = 0; p < 3; ++p) {
                const int unit = tid + p * 512;
                const int row = unit >> 2, su = unit & 3;
                pa[p] = *(const uint4*)(wcat + (size_t)row * kC + k0 + su * 8);
            }
#pragma unroll
            for (int j = 0; j < 8; ++j)
                xv[j] = Xb[(size_t)(k0 + kg * 8 + j) * kN + bn];
        }

        f16x8 bsv[4];
#pragma unroll
        for (int tj = 0; tj < 4; ++tj) {
            const int col = (tj < 2) ? (wc * 32 + tj * 16 + lq)
                                     : (64 + wc * 32 + (tj - 2) * 16 + lq);
            bsv[tj] = *(const f16x8*)&Bs[col * 40 + quad * 8];
        }
        __builtin_amdgcn_s_setprio(1);
#pragma unroll
        for (int ti = 0; ti < 6; ++ti) {
            const f16x8 af = *(const f16x8*)&As[(wr * 96 + ti * 16 + lq) * 40 + quad * 8];
#pragma unroll
            for (int tj = 0; tj < 4; ++tj)
                acc[ti][tj] = __builtin_amdgcn_mfma_f32_16x16x32_f16(
                    af, bsv[tj], acc[ti][tj], 0, 0, 0);
        }
        __builtin_amdgcn_s_setprio(0);
    }

    // ---- epilogues.  D layout: row(ch) = quad*4+r, col(n) = lq per tile ----
#pragma unroll
    for (int ti = 0; ti < 6; ++ti) {
        const int ch0 = wr * 96 + ti * 16;   // wave-uniform
        if (ch0 < 64) {
            // f: unpooled, fT[n][ch], 8B stores
            f16* fb = fT + (size_t)b * kN * kCQ;
#pragma unroll
            for (int tj = 0; tj < 4; ++tj) {
                const int col = (tj < 2) ? (wc * 32 + tj * 16 + lq)
                                         : (64 + wc * 32 + (tj - 2) * 16 + lq);
                const int n = nt * 128 + col;
                union { f16 h4[4]; uint2 u; } pk;
#pragma unroll
                for (int r = 0; r < 4; ++r) pk.h4[r] = (f16)acc[ti][tj][r];
                *(uint2*)(fb + (size_t)n * kCQ + ch0 + quad * 4) = pk.u;
            }
        } else {
            // pooled paths: y-pair = (tj, tj+2), x-pair = lane lq^1
#pragma unroll
            for (int tjp = 0; tjp < 2; ++tjp) {
                float p[4];
#pragma unroll
                for (int r = 0; r < 4; ++r) {
                    float v = fmaxf(acc[ti][tjp][r], acc[ti][tjp + 2][r]);
                    v = fmaxf(v, __shfl_xor(v, 1, 64));
                    p[r] = v;
                }
                const int m = nt * 32 + wc * 16 + tjp * 8 + (lq >> 1);
                if ((lq & 1) == 0) {
                    if (ch0 < 128) {
                        union { f16 h4[4]; uint2 u; } pk;
#pragma unroll
                        for (int r = 0; r < 4; ++r) pk.h4[r] = (f16)p[r];
                        *(uint2*)(gT + ((size_t)b * kM + m) * kCQ + (ch0 - 64) + quad * 4) = pk.u;
                    } else {
#pragma unroll
                        for (int r = 0; r < 4; ++r) {
                            const int ch = ch0 - 128 + quad * 4 + r;
                            h[((size_t)b * kCV + ch) * kM + m] = (f16)p[r];
                        }
                    }
                }
            }
        }
    }
}

// ---------------------------------------------------------------------------
// Kernel 2: MFMA flash attention + fused wo GEMM + residual.
//   NEW: 2 q-tiles (128 q) per block; staged g/h chunk shared by both tiles
//   (40 MFMAs per barrier pair, ha/bg frags reused).  Grid: (32, 16) -> 512
//   blocks = exactly 2/CU, all co-resident.
// ---------------------------------------------------------------------------
__global__ __launch_bounds__(256, 2)
void attn_out_kernel(const f16* __restrict__ fT,
                     const f16* __restrict__ gT,
                     const f16* __restrict__ hmat,
                     const f16* __restrict__ woh,   // gamma*wo, f16 [512][256]
                     const float* __restrict__ x,
                     float* __restrict__ out)
{
    const int qt   = blockIdx.x;   // 0..31: q-base qt*128
    const int b    = blockIdx.y;
    const int tid  = threadIdx.x;
    const int w    = tid >> 6;
    const int lane = tid & 63;
    const int quad = lane >> 4;
    const int lq   = lane & 15;

    __shared__ union alignas(16) SMem {
        struct {
            f16   fsT[128 * 72];   // [q][ch], both tiles
            f16   gsT[32 * 64];    // [m][ch], XOR-swizzled 16B units
            f16   hs[256 * 40];    // [c][m-chunk]
            f16   ps[64 * 40];     // [q-local][m-chunk] (reused A then B)
        } p1;                      // 48128 B
        struct {
            f16 osT[64 * 264];     // [q-local][c] (one tile at a time)
            f16 wos[256 * 40];     // [oc'][k-slab]
        } p2;                      // 54272 B
    } sm;

    // ---- stage fsT [128 q][64 ch] (16 KB) ----
    {
        const f16* fb = fT + ((size_t)b * kN + qt * 128) * kCQ;
#pragma unroll
        for (int p = 0; p < 4; ++p) {
            const int unit = tid + p * 256;
            const int q = unit >> 3, u = unit & 7;
            *(uint4*)&sm.p1.fsT[q * 72 + u * 8] = *(const uint4*)(fb + q * 64 + u * 8);
        }
    }
    __syncthreads();

    // loop-invariant f frags for both tiles (q-local = w*16+lq)
    const f16x8 afA0 = *(const f16x8*)&sm.p1.fsT[(w * 16 + lq) * 72 + quad * 8];
    const f16x8 afA1 = *(const f16x8*)&sm.p1.fsT[(w * 16 + lq) * 72 + 32 + quad * 8];
    const f16x8 afB0 = *(const f16x8*)&sm.p1.fsT[(64 + w * 16 + lq) * 72 + quad * 8];
    const f16x8 afB1 = *(const f16x8*)&sm.p1.fsT[(64 + w * 16 + lq) * 72 + 32 + quad * 8];

    float mA = -3.0e38f, lA = 0.f, mB = -3.0e38f, lB = 0.f;
    f32x4 o_accA[16], o_accB[16];
#pragma unroll
    for (int ci = 0; ci < 16; ++ci) {
        o_accA[ci] = {0.f, 0.f, 0.f, 0.f};
        o_accB[ci] = {0.f, 0.f, 0.f, 0.f};
    }

    const f16* gTb = gT + (size_t)b * kM * kCQ;
    const f16* hb  = hmat + (size_t)b * kCV * kM;

    // ---- prefetch registers for chunk staging ----
    const int gm = tid >> 3, gsu = tid & 7, ggu = gsu ^ (gm & 7);
    const int hc = tid >> 2, hu = tid & 3;
    uint4 pg, ph[4];
    {   // LOAD chunk 0
        pg = *(const uint4*)(gTb + (size_t)gm * kCQ + ggu * 8);
#pragma unroll
        for (int p = 0; p < 4; ++p)
            ph[p] = *(const uint4*)(hb + (size_t)(hc + p * 64) * kM + hu * 8);
    }

    for (int mi = 0; mi < 32; ++mi) {
        __syncthreads();   // prior chunk's LDS reads done
        // ---- write staged regs -> LDS ----
        *(uint4*)&sm.p1.gsT[gm * 64 + gsu * 8] = pg;
#pragma unroll
        for (int p = 0; p < 4; ++p)
            *(uint4*)&sm.p1.hs[(hc + p * 64) * 40 + hu * 8] = ph[p];
        __syncthreads();
        // ---- issue next chunk's loads ----
        if (mi < 31) {
            const int m1 = (mi + 1) * 32;
            pg = *(const uint4*)(gTb + (size_t)(m1 + gm) * kCQ + ggu * 8);
#pragma unroll
            for (int p = 0; p < 4; ++p)
                ph[p] = *(const uint4*)(hb + (size_t)(hc + p * 64) * kM + m1 + hu * 8);
        }

        // ---- S^T = g @ f for both tiles: D[m=quad*4+r (+16)][q=lq] ----
        const int mr0 = lq, mr1 = 16 + lq;
        const f16x8 bg00 = *(const f16x8*)&sm.p1.gsT[mr0 * 64 + ((quad)     ^ (mr0 & 7)) * 8];
        const f16x8 bg01 = *(const f16x8*)&sm.p1.gsT[mr0 * 64 + ((4 + quad) ^ (mr0 & 7)) * 8];
        const f16x8 bg10 = *(const f16x8*)&sm.p1.gsT[mr1 * 64 + ((quad)     ^ (mr1 & 7)) * 8];
        const f16x8 bg11 = *(const f16x8*)&sm.p1.gsT[mr1 * 64 + ((4 + quad) ^ (mr1 & 7)) * 8];
        f32x4 s0A = {0.f,0.f,0.f,0.f}, s1A = {0.f,0.f,0.f,0.f};
        f32x4 s0B = {0.f,0.f,0.f,0.f}, s1B = {0.f,0.f,0.f,0.f};
        s0A = __builtin_amdgcn_mfma_f32_16x16x32_f16(bg00, afA0, s0A, 0, 0, 0);
        s0A = __builtin_amdgcn_mfma_f32_16x16x32_f16(bg01, afA1, s0A, 0, 0, 0);
        s1A = __builtin_amdgcn_mfma_f32_16x16x32_f16(bg10, afA0, s1A, 0, 0, 0);
        s1A = __builtin_amdgcn_mfma_f32_16x16x32_f16(bg11, afA1, s1A, 0, 0, 0);
        s0B = __builtin_amdgcn_mfma_f32_16x16x32_f16(bg00, afB0, s0B, 0, 0, 0);
        s0B = __builtin_amdgcn_mfma_f32_16x16x32_f16(bg01, afB1, s0B, 0, 0, 0);
        s1B = __builtin_amdgcn_mfma_f32_16x16x32_f16(bg10, afB0, s1B, 0, 0, 0);
        s1B = __builtin_amdgcn_mfma_f32_16x16x32_f16(bg11, afB1, s1B, 0, 0, 0);

        // ---- per-lane online softmax, tile A (q = w*16+lq) ----
        float alA;
        {
            float cm = fmaxf(fmaxf(fmaxf(s0A[0], s0A[1]), fmaxf(s0A[2], s0A[3])),
                             fmaxf(fmaxf(s1A[0], s1A[1]), fmaxf(s1A[2], s1A[3])));
            cm = fmaxf(cm, __shfl_xor(cm, 16, 64));
            cm = fmaxf(cm, __shfl_xor(cm, 32, 64));
            const float nm = fmaxf(mA, cm);
            alA = __expf(mA - nm);
            float e0[4], e1[4];
#pragma unroll
            for (int r = 0; r < 4; ++r) { e0[r] = __expf(s0A[r] - nm); e1[r] = __expf(s1A[r] - nm); }
            float psum = (e0[0]+e0[1])+(e0[2]+e0[3])+(e1[0]+e1[1])+(e1[2]+e1[3]);
            psum += __shfl_xor(psum, 16, 64);
            psum += __shfl_xor(psum, 32, 64);
            mA = nm;
            lA = lA * alA + psum;
            union { f16 h4[4]; uint2 u; } pk0, pk1;
#pragma unroll
            for (int r = 0; r < 4; ++r) { pk0.h4[r] = (f16)e0[r]; pk1.h4[r] = (f16)e1[r]; }
            *(uint2*)&sm.p1.ps[(w * 16 + lq) * 40 + quad * 4]      = pk0.u;
            *(uint2*)&sm.p1.ps[(w * 16 + lq) * 40 + 16 + quad * 4] = pk1.u;
        }
        const f16x8 bpA = *(const f16x8*)&sm.p1.ps[(w * 16 + lq) * 40 + quad * 8];
        __builtin_amdgcn_sched_barrier(0);   // bpA read before psB overwrite

        // ---- per-lane online softmax, tile B (q = 64 + w*16+lq) ----
        float alB;
        {
            float cm = fmaxf(fmaxf(fmaxf(s0B[0], s0B[1]), fmaxf(s0B[2], s0B[3])),
                             fmaxf(fmaxf(s1B[0], s1B[1]), fmaxf(s1B[2], s1B[3])));
            cm = fmaxf(cm, __shfl_xor(cm, 16, 64));
            cm = fmaxf(cm, __shfl_xor(cm, 32, 64));
            const float nm = fmaxf(mB, cm);
            alB = __expf(mB - nm);
            float e0[4], e1[4];
#pragma unroll
            for (int r = 0; r < 4; ++r) { e0[r] = __expf(s0B[r] - nm); e1[r] = __expf(s1B[r] - nm); }
            float psum = (e0[0]+e0[1])+(e0[2]+e0[3])+(e1[0]+e1[1])+(e1[2]+e1[3]);
            psum += __shfl_xor(psum, 16, 64);
            psum += __shfl_xor(psum, 32, 64);
            mB = nm;
            lB = lB * alB + psum;
            union { f16 h4[4]; uint2 u; } pk0, pk1;
#pragma unroll
            for (int r = 0; r < 4; ++r) { pk0.h4[r] = (f16)e0[r]; pk1.h4[r] = (f16)e1[r]; }
            *(uint2*)&sm.p1.ps[(w * 16 + lq) * 40 + quad * 4]      = pk0.u;
            *(uint2*)&sm.p1.ps[(w * 16 + lq) * 40 + 16 + quad * 4] = pk1.u;
        }
        const f16x8 bpB = *(const f16x8*)&sm.p1.ps[(w * 16 + lq) * 40 + quad * 8];
        __builtin_amdgcn_sched_barrier(0);

        // ---- PV for both tiles: shared ha reads ----
        __builtin_amdgcn_s_setprio(1);
#pragma unroll
        for (int ci = 0; ci < 16; ++ci) {
            const f16x8 ha = *(const f16x8*)&sm.p1.hs[(ci * 16 + lq) * 40 + quad * 8];
            o_accA[ci] *= alA;
            o_accA[ci] = __builtin_amdgcn_mfma_f32_16x16x32_f16(ha, bpA, o_accA[ci], 0, 0, 0);
            o_accB[ci] *= alB;
            o_accB[ci] = __builtin_amdgcn_mfma_f32_16x16x32_f16(ha, bpB, o_accB[ci], 0, 0, 0);
        }
        __builtin_amdgcn_s_setprio(0);
    }

    const float invA = 1.0f / lA;
    const float invB = 1.0f / lB;

    // ---- prefetch first woh slab ----
    const int woc = tid >> 2, wu = tid & 3;
    uint4 pw[4];
#pragma unroll
    for (int p = 0; p < 4; ++p)
        pw[p] = *(const uint4*)(woh + (size_t)(woc + p * 64) * 256 + wu * 8);

    __syncthreads();   // all waves done with p1 before p2 clobber

    // ---- dump tile A -> osT (packed 8B, rows wave-private) ----
#pragma unroll
    for (int ci = 0; ci < 16; ++ci) {
        union { f16 h4[4]; uint2 u; } pk;
#pragma unroll
        for (int r = 0; r < 4; ++r) pk.h4[r] = (f16)(o_accA[ci][r] * invA);
        *(uint2*)&sm.p2.osT[(w * 16 + lq) * 264 + ci * 16 + quad * 4] = pk.u;
    }

    // ---- GEMM2 x2 tiles: out = woh @ o + x ----
    int s = 0;
    for (int tile = 0; tile < 2; ++tile) {
        for (int half = 0; half < 2; ++half) {
            f32x4 acc2[16];
#pragma unroll
            for (int os = 0; os < 16; ++os) acc2[os] = {0.f, 0.f, 0.f, 0.f};

            for (int ck = 0; ck < 8; ++ck) {
                __syncthreads();   // prev slab reads done
#pragma unroll
                for (int p = 0; p < 4; ++p)
                    *(uint4*)&sm.p2.wos[(woc + p * 64) * 40 + wu * 8] = pw[p];
                __syncthreads();
                ++s;
                if (s < 32) {   // issue next slab's loads
                    const int sp = s & 15;
#pragma unroll
                    for (int p = 0; p < 4; ++p)
                        pw[p] = *(const uint4*)(woh +
                            (size_t)((sp >> 3) * 256 + woc + p * 64) * 256 +
                            (sp & 7) * 32 + wu * 8);
                }
                const f16x8 bo = *(const f16x8*)&sm.p2.osT[(w * 16 + lq) * 264 + ck * 32 + quad * 8];
                __builtin_amdgcn_s_setprio(1);
#pragma unroll
                for (int os = 0; os < 16; ++os) {
                    const f16x8 wa = *(const f16x8*)&sm.p2.wos[(os * 16 + lq) * 40 + quad * 8];
                    acc2[os] = __builtin_amdgcn_mfma_f32_16x16x32_f16(wa, bo, acc2[os], 0, 0, 0);
                }
                __builtin_amdgcn_s_setprio(0);
            }

            const int n0 = qt * 128 + tile * 64 + w * 16 + lq;
#pragma unroll
            for (int os = 0; os < 16; ++os) {
#pragma unroll
                for (int r = 0; r < 4; ++r) {
                    const int oc = half * 256 + os * 16 + quad * 4 + r;
                    const size_t idx = ((size_t)b * kC + oc) * (size_t)kN + n0;
                    out[idx] = acc2[os][r] + x[idx];
                }
            }
        }
        if (tile == 0) {
            // dump tile B -> osT (rows wave-private; this wave's reads done)
#pragma unroll
            for (int ci = 0; ci < 16; ++ci) {
                union { f16 h4[4]; uint2 u; } pk;
#pragma unroll
                for (int r = 0; r < 4; ++r) pk.h4[r] = (f16)(o_accB[ci][r] * invB);
                *(uint2*)&sm.p2.osT[(w * 16 + lq) * 264 + ci * 16 + quad * 4] = pk.u;
            }
        }
    }
}

}  // namespace

extern "C" void kernel_launch(void* const* d_in, const int* in_sizes, int n_in,
                              void* d_out, int out_size, void* d_ws, size_t ws_size,
                              hipStream_t stream) {
    const float* x     = (const float*)d_in[0];
    const float* wq    = (const float*)d_in[1];
    const float* wk    = (const float*)d_in[2];
    const float* wv    = (const float*)d_in[3];
    const float* wo    = (const float*)d_in[4];
    const float* gamma = (const float*)d_in[5];
    float* out = (float*)d_out;

    f16* fT   = (f16*)d_ws;
    f16* gT   = fT  + (size_t)kB * kN * kCQ;
    f16* hw   = gT  + (size_t)kB * kM * kCQ;
    f16* woh  = hw  + (size_t)kB * kCV * kM;
    f16* wcat = woh + (size_t)kC * kCV;

    hipLaunchKernelGGL(convert_weights_kernel, dim3(320), dim3(256), 0, stream,
                       wq, wk, wv, wo, gamma, wcat, woh);
    hipLaunchKernelGGL(proj_pool_mfma, dim3(32, kB), dim3(512), 0, stream,
                       x, wcat, fT, gT, hw);
    hipLaunchKernelGGL(attn_out_kernel, dim3(32, kB), dim3(256), 0, stream,
                       fT, gT, hw, woh, x, out);
}